// Round 4
// baseline (269.380 us; speedup 1.0000x reference)
//
#include <hip/hip_runtime.h>
#include <stdint.h>

typedef float f32x4 __attribute__((ext_vector_type(4)));
typedef __bf16 bf16x8 __attribute__((ext_vector_type(8)));
typedef unsigned short u16;
typedef u16 u16x8 __attribute__((ext_vector_type(8)));

__device__ __forceinline__ u16 f2bf(float f) {
  uint32_t u = __builtin_bit_cast(uint32_t, f);
  return (u16)((u + 0x7fffu + ((u >> 16) & 1u)) >> 16);
}
__device__ __forceinline__ float bf2f(u16 h) {
  uint32_t u = ((uint32_t)h) << 16;
  return __builtin_bit_cast(float, u);
}
__device__ __forceinline__ float elup1(float x) {
  return x > 0.f ? x + 1.f : __expf(x);
}
__device__ __forceinline__ void gll16(const void* g, void* l) {
  __builtin_amdgcn_global_load_lds(
      (const __attribute__((address_space(1))) unsigned int*)g,
      (__attribute__((address_space(3))) unsigned int*)l, 16, 0, 0);
}

#define BAR() __builtin_amdgcn_s_barrier()
#define VMC(n) asm volatile("s_waitcnt vmcnt(" #n ")" ::: "memory")

// ---------------- f32 -> bf16 conversion (4 elems/thread) ----------------
__global__ void cvt_kernel(const float* __restrict__ in, u16* __restrict__ out, int n4) {
  int i = blockIdx.x * 256 + threadIdx.x;
  if (i >= n4) return;
  float4 f = ((const float4*)in)[i];
  ushort4 o;
  o.x = f2bf(f.x); o.y = f2bf(f.y); o.z = f2bf(f.z); o.w = f2bf(f.w);
  ((ushort4*)out)[i] = o;
}

// ============ 256x256 8-phase bf16 GEMM  C[M,N] = A[M,K]*B[N,K]^T =========
// 512 threads (8 waves, 2M x 4N). BK=64. LDS 128 KiB (2 dbuf x (A 32K + B 32K)).
// Swizzle: stored colbyte = logical colbyte ^ ((ldsrow&7)<<4); gll dest linear,
// source pre-swizzled (rule #21).
// NOTE: no explicit lgkmcnt drain before MFMA — compiler emits fine-grained
// lgkmcnt for register-consumed ds_reads; all reads of a phase are consumed
// by that phase's MFMA cluster, so WAR vs later gll16 stays barrier-protected.
// EPI==0: qkv epilogue (bias + elu+1 on cols<2048, bf16 store, LDS-coalesced)
// EPI==1: out epilogue (bias, f32 store — already line-coalesced)
template <int EPI>
__global__ __launch_bounds__(512, 2)
void gemm256(const u16* __restrict__ A, const u16* __restrict__ B,
             const float* __restrict__ bias, void* __restrict__ Cout,
             int N, int K, int nbj) {
  __shared__ __align__(16) u16 lds[65536];  // 128 KiB
  const int tid = threadIdx.x;
  const int wave = tid >> 6, lane = tid & 63;
  const int fr = lane & 15, fq = lane >> 4;
  const int wm = wave >> 2, wn = wave & 3;

  // XCD-aware bijective block swizzle (grid % 8 == 0 by construction)
  const int nwg = gridDim.x;
  const int cpx = nwg >> 3;
  const int swz = (blockIdx.x & 7) * cpx + (blockIdx.x >> 3);
  const int bi = swz / nbj, bj = swz % nbj;

  const u16* Ab = A + (size_t)bi * 256 * K;
  const u16* Bb = B + (size_t)bj * 256 * K;

  // staging geometry: per inst, thread covers LDS bytes i*8192 + wave*1024 + lane*16
  const int l8 = lane >> 3;                       // ldsrow & 7
  const int cswz = ((lane & 7) ^ l8) << 3;        // swizzled col offset (elements)
  const int r6 = wave * 8 + l8;                   // row within 64-row inst block

#define STAGE_A(d, h, k0)                                                      \
  { _Pragma("unroll")                                                          \
    for (int i_ = 0; i_ < 2; ++i_) {                                           \
      int gr_ = i_ * 128 + (h) * 64 + r6;                                      \
      gll16(Ab + (size_t)gr_ * K + (k0) + cswz,                                \
            &lds[((d) * 32768 + (h) * 16384 + i_ * 8192 + wave * 1024) >> 1]); \
    } }

#define STAGE_B(d, h, k0)                                                      \
  { _Pragma("unroll")                                                          \
    for (int i_ = 0; i_ < 2; ++i_) {                                           \
      int r_ = i_ * 64 + r6;                                                   \
      int gr_ = (r_ >> 5) * 64 + (h) * 32 + (r_ & 31);                         \
      gll16(Bb + (size_t)gr_ * K + (k0) + cswz,                                \
            &lds[(65536 + (d) * 32768 + (h) * 16384 + i_ * 8192 + wave * 1024) >> 1]); \
    } }

  // fragment-read addressing (bytes)
  const int xorc = (fr & 7) << 4;
  const int acol[2] = {(fq * 16) ^ xorc, (64 + fq * 16) ^ xorc};
  const int arow = (wm * 64 + fr) * 128;  // + mm*2048
  const int brow = (wn * 32 + fr) * 128;  // + nn*2048

#define LDSV(off) (*(const bf16x8*)&lds[(off) >> 1])

  f32x4 acc[8][4] = {};
  bf16x8 af[4][2];       // A frags of current m-half
  bf16x8 bfr[2][2][2];   // B frags [nh][nn][ks], both halves kept live

  // ks-major issue order: the ks=0 operands arrive first, feeding the ks=0
  // MFMA wave while ks=1 reads are still in flight (compiler fine-grains).
#define READ_A(d, mh)                                                          \
  { _Pragma("unroll")                                                          \
    for (int ks = 0; ks < 2; ++ks) {                                           \
      _Pragma("unroll")                                                        \
      for (int mm = 0; mm < 4; ++mm)                                           \
        af[mm][ks] = LDSV((d) * 32768 + (mh) * 16384 + arow + mm * 2048 + acol[ks]); \
    } }

#define READ_B(d, nh)                                                          \
  { _Pragma("unroll")                                                          \
    for (int ks = 0; ks < 2; ++ks) {                                           \
      _Pragma("unroll")                                                        \
      for (int nn = 0; nn < 2; ++nn)                                           \
        bfr[nh][nn][ks] = LDSV(65536 + (d) * 32768 + (nh) * 16384 + brow + nn * 2048 + acol[ks]); \
    } }

  // ks-outer: 8 independent MFMAs between same-acc reuses (no dep stalls)
#define MFMA_Q(mh, nh)                                                         \
  { __builtin_amdgcn_s_setprio(1);                                             \
    _Pragma("unroll")                                                          \
    for (int ks = 0; ks < 2; ++ks) {                                           \
      _Pragma("unroll")                                                        \
      for (int mm = 0; mm < 4; ++mm) {                                         \
        _Pragma("unroll")                                                      \
        for (int nn = 0; nn < 2; ++nn)                                         \
          acc[(mh) * 4 + mm][(nh) * 2 + nn] = __builtin_amdgcn_mfma_f32_16x16x32_bf16( \
              af[mm][ks], bfr[nh][nn][ks], acc[(mh) * 4 + mm][(nh) * 2 + nn], 0, 0, 0); \
      } }                                                                      \
    __builtin_amdgcn_s_setprio(0); }

  const int NT = K >> 6;
  // prologue: t0 all 4 halves, then t1's first 3; counted waits (4 then 6)
  STAGE_A(0, 0, 0); STAGE_B(0, 0, 0); STAGE_B(0, 1, 0); STAGE_A(0, 1, 0);
  VMC(4);
  STAGE_A(1, 0, 64); STAGE_B(1, 0, 64); STAGE_B(1, 1, 64);
  VMC(6);
  BAR();

  for (int t = 0; t < NT; ++t) {
    const int d = t & 1;
    const int k1 = (t + 1) << 6, k2 = (t + 2) << 6;
    // ---- P1: quadrant (mh0, nh0)
    READ_B(d, 0); READ_A(d, 0);
    if (t + 1 < NT) STAGE_A(d ^ 1, 1, k1);
    BAR(); MFMA_Q(0, 0); BAR();
    // ---- P2: quadrant (mh0, nh1)
    READ_B(d, 1);
    if (t + 2 < NT) STAGE_A(d, 0, k2);
    BAR(); MFMA_Q(0, 1); BAR();
    // ---- P3: quadrant (mh1, nh1)
    READ_A(d, 1);
    if (t + 2 < NT) STAGE_B(d, 0, k2);
    BAR(); MFMA_Q(1, 1); BAR();
    // ---- P4: quadrant (mh1, nh0) — B nh0 still live in regs
    if (t + 2 < NT) STAGE_B(d, 1, k2);
    BAR(); MFMA_Q(1, 0);
    if (t < NT - 2) { VMC(6); }
    else if (t == NT - 2) { VMC(0); }
    BAR();
  }

  // ---- epilogue (after final BAR all waves are past all LDS reads)
  const int wrow = wm * 128, wcol = wn * 64;
  if (EPI == 0) {
    // block is entirely q/k (elu) or entirely v: 2048 is 256-aligned
    const bool do_elu = (bj * 256) < 2048;
    float bv[4];
#pragma unroll
    for (int n = 0; n < 4; ++n) bv[n] = bias[bj * 256 + wcol + n * 16 + fr];
    u16* wbuf = &lds[wave * 8192];  // wave-private 16 KiB
    const int lrow = lane >> 3, lcol = (lane & 7) * 8;
#pragma unroll
    for (int ch = 0; ch < 2; ++ch) {
#pragma unroll
      for (int m2 = 0; m2 < 4; ++m2)
#pragma unroll
        for (int n = 0; n < 4; ++n)
#pragma unroll
          for (int r = 0; r < 4; ++r) {
            float v = acc[ch * 4 + m2][n][r] + bv[n];
            if (do_elu) v = elup1(v);
            wbuf[(m2 * 16 + fq * 4 + r) * 72 + n * 16 + fr] = f2bf(v);
          }
      // per-wave LDS ops are in-order: cross-lane read-back is safe sans barrier
#pragma unroll
      for (int i = 0; i < 8; ++i) {
        bf16x8 val = *(const bf16x8*)&wbuf[(i * 8 + lrow) * 72 + lcol];
        const int rowg = bi * 256 + wrow + ch * 64 + i * 8 + lrow;
        *(bf16x8*)&((u16*)Cout)[(size_t)rowg * N + bj * 256 + wcol + lcol] = val;
      }
    }
  } else {
#pragma unroll
    for (int n = 0; n < 4; ++n) {
      const int colg = bj * 256 + wcol + n * 16 + fr;
      const float bv = bias[colg];
#pragma unroll
      for (int m = 0; m < 8; ++m)
#pragma unroll
        for (int r = 0; r < 4; ++r) {
          const int rowg = bi * 256 + wrow + m * 16 + fq * 4 + r;
          ((float*)Cout)[(size_t)rowg * N + colg] = acc[m][n][r] + bv;
        }
    }
  }
#undef STAGE_A
#undef STAGE_B
#undef READ_A
#undef READ_B
#undef MFMA_Q
#undef LDSV
}

// ---------------- kv state partials: kv[d][e] = sum_s k[s,d]*v[s,e] -------
// grid: (64 bh, 8 s-chunks of 512); block 256
__global__ __launch_bounds__(256)
void kv_state_kernel(const u16* __restrict__ qkv, float* __restrict__ pkv,
                     float* __restrict__ pks) {
  const int bh = blockIdx.x, chunk = blockIdx.y;
  const int b = bh >> 4, h = bh & 15;
  const int t = threadIdx.x;
  __shared__ float sK[16][68];
  __shared__ float sV[16][68];
  const int td = t >> 2;
  const int te = (t & 3) * 16;
  f32x4 acc0 = {}, acc1 = {}, acc2 = {}, acc3 = {};
  float aks = 0.f;
  const size_t rowbase = ((size_t)b * 4096 + (size_t)chunk * 512) * 3072;
  const u16* kp = qkv + rowbase + 1024 + h * 64;
  const u16* vp = qkv + rowbase + 2048 + h * 64;
  // vectorized staging: 128 threads for K, 128 for V; 16B/lane
  const int lhalf = t >> 7, lr = (t >> 3) & 15, lc = (t & 7) * 8;
  const u16* lsrc = lhalf ? vp : kp;
  float* ldst = lhalf ? &sV[lr][lc] : &sK[lr][lc];
  for (int s0 = 0; s0 < 512; s0 += 16) {
    u16x8 v8 = *(const u16x8*)&lsrc[(size_t)(s0 + lr) * 3072 + lc];
#pragma unroll
    for (int j = 0; j < 8; ++j) ldst[j] = bf2f(v8[j]);
    __syncthreads();
#pragma unroll 4
    for (int sl = 0; sl < 16; ++sl) {
      float kd = sK[sl][td];
      if ((t & 3) == 0) aks += kd;
      const f32x4* v4 = (const f32x4*)&sV[sl][te];
      acc0 += kd * v4[0];
      acc1 += kd * v4[1];
      acc2 += kd * v4[2];
      acc3 += kd * v4[3];
    }
    __syncthreads();
  }
  float* outp = pkv + ((size_t)chunk * 64 + bh) * 4096 + td * 64 + te;
  *(f32x4*)(outp + 0) = acc0;
  *(f32x4*)(outp + 4) = acc1;
  *(f32x4*)(outp + 8) = acc2;
  *(f32x4*)(outp + 12) = acc3;
  if ((t & 3) == 0) pks[((size_t)chunk * 64 + bh) * 64 + td] = aks;
}

// ---------------- reduce partials, fold division --------------------------
__global__ __launch_bounds__(256)
void kv_reduce_kernel(const float* __restrict__ pkv, const float* __restrict__ pks,
                      float* __restrict__ kvn) {
  const int bh = blockIdx.x;
  const int t = threadIdx.x;
  __shared__ float sks[64];
  if (t < 64) {
    float s = 0.f;
    for (int c = 0; c < 8; ++c) s += pks[((size_t)c * 64 + bh) * 64 + t];
    sks[t] = s + 1e-6f;
  }
  __syncthreads();
#pragma unroll
  for (int j = 0; j < 16; ++j) {
    int idx = t + j * 256;
    float s = 0.f;
    for (int c = 0; c < 8; ++c) s += pkv[((size_t)c * 64 + bh) * 4096 + idx];
    kvn[(size_t)bh * 4096 + idx] = s / sks[idx & 63];
  }
}

// ---------------- attn out: o[s,e] = sum_d q[s,d]*kvn[d,e] via MFMA -------
// grid: (64 bh, 64 s-tiles of 64 rows); block 256 (4 waves x 16 rows)
__global__ __launch_bounds__(256)
void attn_out_kernel(const u16* __restrict__ qkv, const float* __restrict__ kvn,
                     u16* __restrict__ attn) {
  const int bh = blockIdx.x;
  const int b = bh >> 4, h = bh & 15;
  const int stile = blockIdx.y;
  const int wave = threadIdx.x >> 6, lane = threadIdx.x & 63;
  const int s0 = stile * 64 + wave * 16;
  const int fr = lane & 15, fq = lane >> 4;
  __shared__ u16 sO[4][16 * 72];
  const float* kv = kvn + (size_t)bh * 4096;
  bf16x8 bfrag[2][4];
#pragma unroll
  for (int ks = 0; ks < 2; ++ks)
#pragma unroll
    for (int n = 0; n < 4; ++n) {
      u16x8 tmp;
#pragma unroll
      for (int j = 0; j < 8; ++j)
        tmp[j] = f2bf(kv[(size_t)(ks * 32 + fq * 8 + j) * 64 + n * 16 + fr]);
      bfrag[ks][n] = __builtin_bit_cast(bf16x8, tmp);
    }
  const u16* q = qkv + (size_t)b * 4096 * 3072 + h * 64;
  f32x4 acc[4] = {};
#pragma unroll
  for (int ks = 0; ks < 2; ++ks) {
    bf16x8 af = *(const bf16x8*)&q[(size_t)(s0 + fr) * 3072 + ks * 32 + fq * 8];
#pragma unroll
    for (int n = 0; n < 4; ++n)
      acc[n] = __builtin_amdgcn_mfma_f32_16x16x32_bf16(af, bfrag[ks][n], acc[n], 0, 0, 0);
  }
  // coalesced store via per-wave LDS staging
  u16* wb = &sO[wave][0];
#pragma unroll
  for (int n = 0; n < 4; ++n)
#pragma unroll
    for (int r = 0; r < 4; ++r)
      wb[(fq * 4 + r) * 72 + n * 16 + fr] = f2bf(acc[n][r]);
  u16* ap = attn + (size_t)b * 4096 * 1024 + h * 64;
  const int lrow = lane >> 3, lcol = (lane & 7) * 8;
#pragma unroll
  for (int i = 0; i < 2; ++i) {
    bf16x8 val = *(const bf16x8*)&wb[(i * 8 + lrow) * 72 + lcol];
    *(bf16x8*)&ap[(size_t)(s0 + i * 8 + lrow) * 1024 + lcol] = val;
  }
}

// -------------------------------------------------------------------------
extern "C" void kernel_launch(void* const* d_in, const int* in_sizes, int n_in,
                              void* d_out, int out_size, void* d_ws, size_t ws_size,
                              hipStream_t stream) {
  const float* x     = (const float*)d_in[0];
  const float* w_qkv = (const float*)d_in[1];
  const float* b_qkv = (const float*)d_in[2];
  const float* w_out = (const float*)d_in[3];
  const float* b_out = (const float*)d_in[4];
  float* out = (float*)d_out;

  const int M = 16384, Dm = 1024, N3 = 3072;

  char* ws = (char*)d_ws;
  u16* xb     = (u16*)(ws);                    //  33,554,432 B
  u16* wqb    = (u16*)(ws + 33554432);         //   6,291,456 B
  u16* wob    = (u16*)(ws + 39845888);         //   2,097,152 B
  u16* qkvb   = (u16*)(ws + 41943040);         // 100,663,296 B
  u16* attnb  = (u16*)(ws + 142606336);        //  33,554,432 B
  float* pkv  = (float*)(ws + 176160768);      //   8,388,608 B
  float* pks  = (float*)(ws + 184549376);      //     131,072 B
  float* kvn  = (float*)(ws + 184680448);      //   1,048,576 B

  cvt_kernel<<<(M * Dm / 4 + 255) / 256, 256, 0, stream>>>(x, xb, M * Dm / 4);
  cvt_kernel<<<(N3 * Dm / 4 + 255) / 256, 256, 0, stream>>>(w_qkv, wqb, N3 * Dm / 4);
  cvt_kernel<<<(Dm * Dm / 4 + 255) / 256, 256, 0, stream>>>(w_out, wob, Dm * Dm / 4);

  gemm256<0><<<(M / 256) * (N3 / 256), 512, 0, stream>>>(xb, wqb, b_qkv, qkvb, N3, Dm, N3 / 256);
  kv_state_kernel<<<dim3(64, 8), 256, 0, stream>>>(qkvb, pkv, pks);
  kv_reduce_kernel<<<64, 256, 0, stream>>>(pkv, pks, kvn);
  attn_out_kernel<<<dim3(64, 64), 256, 0, stream>>>(qkvb, kvn, attnb);
  gemm256<1><<<(M / 256) * (Dm / 256), 512, 0, stream>>>(attnb, wob, b_out, out, Dm, Dm, Dm / 256);
}

// Round 5
// 264.449 us; speedup vs baseline: 1.0186x; 1.0186x over previous
//
#include <hip/hip_runtime.h>
#include <stdint.h>

typedef float f32x4 __attribute__((ext_vector_type(4)));
typedef __bf16 bf16x8 __attribute__((ext_vector_type(8)));
typedef unsigned short u16;
typedef u16 u16x8 __attribute__((ext_vector_type(8)));

__device__ __forceinline__ u16 f2bf(float f) {
  uint32_t u = __builtin_bit_cast(uint32_t, f);
  return (u16)((u + 0x7fffu + ((u >> 16) & 1u)) >> 16);
}
__device__ __forceinline__ float bf2f(u16 h) {
  uint32_t u = ((uint32_t)h) << 16;
  return __builtin_bit_cast(float, u);
}
__device__ __forceinline__ float elup1(float x) {
  return x > 0.f ? x + 1.f : __expf(x);
}
__device__ __forceinline__ void gll16(const void* g, void* l) {
  __builtin_amdgcn_global_load_lds(
      (const __attribute__((address_space(1))) unsigned int*)g,
      (__attribute__((address_space(3))) unsigned int*)l, 16, 0, 0);
}

#define BAR() __builtin_amdgcn_s_barrier()
#define VMC(n) asm volatile("s_waitcnt vmcnt(" #n ")" ::: "memory")

// ---------------- f32 -> bf16 conversion (4 elems/thread) ----------------
__global__ void cvt_kernel(const float* __restrict__ in, u16* __restrict__ out, int n4) {
  int i = blockIdx.x * 256 + threadIdx.x;
  if (i >= n4) return;
  float4 f = ((const float4*)in)[i];
  ushort4 o;
  o.x = f2bf(f.x); o.y = f2bf(f.y); o.z = f2bf(f.z); o.w = f2bf(f.w);
  ((ushort4*)out)[i] = o;
}

// ============ 256x256 bf16 GEMM  C[M,N] = A[M,K]*B[N,K]^T =================
// 512 threads (8 waves, 2M x 4N). BK=64. LDS 128 KiB (2 dbuf x (A 32K + B 32K)).
// FREE-RUN schedule: only 2 barriers per K-tile.
//   q0: read A0,B0(d); stage t+1.A1->d^1 ; MFMA(A0,B0)
//   q1: read B1(d)                       ; MFMA(A0,B1)
//   BAR_MID   // every wave has issued MFMA(q1) => its A0,B0,B1 LDS reads are
//             // register-resident => safe to overwrite those regions of d
//   q2: read A1(d); stage t+2.{A0,B0}->d ; MFMA(A1,B1)
//   q3: stage t+2.B1->d                  ; MFMA(A1,B0)
//   VMC(6); BAR_END  // t+1's buffer fully landed; newest 6 loads (t+2) remain
// Waves free-run between barriers: per-register lgkm deps overlap one wave's
// MFMA with another's LDS reads (the per-phase barrier pair serialized them).
// Swizzle: stored colbyte = logical colbyte ^ ((ldsrow&7)<<4); gll dest linear,
// source pre-swizzled (rule #21).
// EPI==0: qkv epilogue (bias + elu+1 on cols<2048, bf16 store, LDS-coalesced)
// EPI==1: out epilogue (bias, f32 store — already line-coalesced)
template <int EPI>
__global__ __launch_bounds__(512, 2)
void gemm256(const u16* __restrict__ A, const u16* __restrict__ B,
             const float* __restrict__ bias, void* __restrict__ Cout,
             int N, int K, int nbj) {
  __shared__ __align__(16) u16 lds[65536];  // 128 KiB
  const int tid = threadIdx.x;
  const int wave = tid >> 6, lane = tid & 63;
  const int fr = lane & 15, fq = lane >> 4;
  const int wm = wave >> 2, wn = wave & 3;

  // XCD-aware bijective block swizzle (grid % 8 == 0 by construction)
  const int nwg = gridDim.x;
  const int cpx = nwg >> 3;
  const int swz = (blockIdx.x & 7) * cpx + (blockIdx.x >> 3);
  const int bi = swz / nbj, bj = swz % nbj;

  const u16* Ab = A + (size_t)bi * 256 * K;
  const u16* Bb = B + (size_t)bj * 256 * K;

  // staging geometry: per inst, thread covers LDS bytes i*8192 + wave*1024 + lane*16
  const int l8 = lane >> 3;                       // ldsrow & 7
  const int cswz = ((lane & 7) ^ l8) << 3;        // swizzled col offset (elements)
  const int r6 = wave * 8 + l8;                   // row within 64-row inst block

#define STAGE_A(d, h, k0)                                                      \
  { _Pragma("unroll")                                                          \
    for (int i_ = 0; i_ < 2; ++i_) {                                           \
      int gr_ = i_ * 128 + (h) * 64 + r6;                                      \
      gll16(Ab + (size_t)gr_ * K + (k0) + cswz,                                \
            &lds[((d) * 32768 + (h) * 16384 + i_ * 8192 + wave * 1024) >> 1]); \
    } }

#define STAGE_B(d, h, k0)                                                      \
  { _Pragma("unroll")                                                          \
    for (int i_ = 0; i_ < 2; ++i_) {                                           \
      int r_ = i_ * 64 + r6;                                                   \
      int gr_ = (r_ >> 5) * 64 + (h) * 32 + (r_ & 31);                         \
      gll16(Bb + (size_t)gr_ * K + (k0) + cswz,                                \
            &lds[(65536 + (d) * 32768 + (h) * 16384 + i_ * 8192 + wave * 1024) >> 1]); \
    } }

  // fragment-read addressing (bytes)
  const int xorc = (fr & 7) << 4;
  const int acol[2] = {(fq * 16) ^ xorc, (64 + fq * 16) ^ xorc};
  const int arow = (wm * 64 + fr) * 128;  // + mm*2048
  const int brow = (wn * 32 + fr) * 128;  // + nn*2048

#define LDSV(off) (*(const bf16x8*)&lds[(off) >> 1])

  f32x4 acc[8][4] = {};
  bf16x8 af[4][2];       // A frags of current m-half
  bf16x8 bfr[2][2][2];   // B frags [nh][nn][ks], both halves kept live

#define READ_A(d, mh)                                                          \
  { _Pragma("unroll")                                                          \
    for (int ks = 0; ks < 2; ++ks) {                                           \
      _Pragma("unroll")                                                        \
      for (int mm = 0; mm < 4; ++mm)                                           \
        af[mm][ks] = LDSV((d) * 32768 + (mh) * 16384 + arow + mm * 2048 + acol[ks]); \
    } }

#define READ_B(d, nh)                                                          \
  { _Pragma("unroll")                                                          \
    for (int ks = 0; ks < 2; ++ks) {                                           \
      _Pragma("unroll")                                                        \
      for (int nn = 0; nn < 2; ++nn)                                           \
        bfr[nh][nn][ks] = LDSV(65536 + (d) * 32768 + (nh) * 16384 + brow + nn * 2048 + acol[ks]); \
    } }

  // ks-outer: 8 independent MFMAs between same-acc reuses (no dep stalls)
#define MFMA_Q(mh, nh)                                                         \
  { __builtin_amdgcn_s_setprio(1);                                             \
    _Pragma("unroll")                                                          \
    for (int ks = 0; ks < 2; ++ks) {                                           \
      _Pragma("unroll")                                                        \
      for (int mm = 0; mm < 4; ++mm) {                                         \
        _Pragma("unroll")                                                      \
        for (int nn = 0; nn < 2; ++nn)                                         \
          acc[(mh) * 4 + mm][(nh) * 2 + nn] = __builtin_amdgcn_mfma_f32_16x16x32_bf16( \
              af[mm][ks], bfr[nh][nn][ks], acc[(mh) * 4 + mm][(nh) * 2 + nn], 0, 0, 0); \
      } }                                                                      \
    __builtin_amdgcn_s_setprio(0); }

  const int NT = K >> 6;
  // prologue: t0 all 4 halves, then t1's {A0,B0,B1}; one counted wait
  STAGE_A(0, 0, 0); STAGE_B(0, 0, 0); STAGE_B(0, 1, 0); STAGE_A(0, 1, 0);
  STAGE_A(1, 0, 64); STAGE_B(1, 0, 64); STAGE_B(1, 1, 64);
  VMC(6);
  BAR();

  for (int t = 0; t < NT; ++t) {
    const int d = t & 1;
    const int k1 = (t + 1) << 6, k2 = (t + 2) << 6;
    // ---- q0: (A0,B0)
    READ_B(d, 0); READ_A(d, 0);
    if (t + 1 < NT) STAGE_A(d ^ 1, 1, k1);
    MFMA_Q(0, 0);
    // ---- q1: (A0,B1)
    READ_B(d, 1);
    MFMA_Q(0, 1);
    BAR();  // MID: all waves' A0,B0,B1 reads are register-resident
    // ---- q2: (A1,B1)
    READ_A(d, 1);
    if (t + 2 < NT) { STAGE_A(d, 0, k2); STAGE_B(d, 0, k2); }
    MFMA_Q(1, 1);
    // ---- q3: (A1,B0) — B0 still live in regs since q0
    if (t + 2 < NT) STAGE_B(d, 1, k2);
    MFMA_Q(1, 0);
    if (t < NT - 2) { VMC(6); } else { VMC(0); }
    BAR();  // END: next tile's buffer fully landed
  }

  // ---- epilogue (after final BAR all waves are past all LDS reads)
  const int wrow = wm * 128, wcol = wn * 64;
  if (EPI == 0) {
    // block is entirely q/k (elu) or entirely v: 2048 is 256-aligned
    const bool do_elu = (bj * 256) < 2048;
    float bv[4];
#pragma unroll
    for (int n = 0; n < 4; ++n) bv[n] = bias[bj * 256 + wcol + n * 16 + fr];
    u16* wbuf = &lds[wave * 8192];  // wave-private 16 KiB
    const int lrow = lane >> 3, lcol = (lane & 7) * 8;
#pragma unroll
    for (int ch = 0; ch < 2; ++ch) {
#pragma unroll
      for (int m2 = 0; m2 < 4; ++m2)
#pragma unroll
        for (int n = 0; n < 4; ++n)
#pragma unroll
          for (int r = 0; r < 4; ++r) {
            float v = acc[ch * 4 + m2][n][r] + bv[n];
            if (do_elu) v = elup1(v);
            wbuf[(m2 * 16 + fq * 4 + r) * 72 + n * 16 + fr] = f2bf(v);
          }
      // per-wave LDS ops are in-order: cross-lane read-back is safe sans barrier
#pragma unroll
      for (int i = 0; i < 8; ++i) {
        bf16x8 val = *(const bf16x8*)&wbuf[(i * 8 + lrow) * 72 + lcol];
        const int rowg = bi * 256 + wrow + ch * 64 + i * 8 + lrow;
        *(bf16x8*)&((u16*)Cout)[(size_t)rowg * N + bj * 256 + wcol + lcol] = val;
      }
    }
  } else {
#pragma unroll
    for (int n = 0; n < 4; ++n) {
      const int colg = bj * 256 + wcol + n * 16 + fr;
      const float bv = bias[colg];
#pragma unroll
      for (int m = 0; m < 8; ++m)
#pragma unroll
        for (int r = 0; r < 4; ++r) {
          const int rowg = bi * 256 + wrow + m * 16 + fq * 4 + r;
          ((float*)Cout)[(size_t)rowg * N + colg] = acc[m][n][r] + bv;
        }
    }
  }
#undef STAGE_A
#undef STAGE_B
#undef READ_A
#undef READ_B
#undef MFMA_Q
#undef LDSV
}

// ---------------- kv state partials: kv[d][e] = sum_s k[s,d]*v[s,e] -------
// grid: (64 bh, 8 s-chunks of 512); block 256
__global__ __launch_bounds__(256)
void kv_state_kernel(const u16* __restrict__ qkv, float* __restrict__ pkv,
                     float* __restrict__ pks) {
  const int bh = blockIdx.x, chunk = blockIdx.y;
  const int b = bh >> 4, h = bh & 15;
  const int t = threadIdx.x;
  __shared__ float sK[16][68];
  __shared__ float sV[16][68];
  const int td = t >> 2;
  const int te = (t & 3) * 16;
  f32x4 acc0 = {}, acc1 = {}, acc2 = {}, acc3 = {};
  float aks = 0.f;
  const size_t rowbase = ((size_t)b * 4096 + (size_t)chunk * 512) * 3072;
  const u16* kp = qkv + rowbase + 1024 + h * 64;
  const u16* vp = qkv + rowbase + 2048 + h * 64;
  // vectorized staging: 128 threads for K, 128 for V; 16B/lane
  const int lhalf = t >> 7, lr = (t >> 3) & 15, lc = (t & 7) * 8;
  const u16* lsrc = lhalf ? vp : kp;
  float* ldst = lhalf ? &sV[lr][lc] : &sK[lr][lc];
  for (int s0 = 0; s0 < 512; s0 += 16) {
    u16x8 v8 = *(const u16x8*)&lsrc[(size_t)(s0 + lr) * 3072 + lc];
#pragma unroll
    for (int j = 0; j < 8; ++j) ldst[j] = bf2f(v8[j]);
    __syncthreads();
#pragma unroll 4
    for (int sl = 0; sl < 16; ++sl) {
      float kd = sK[sl][td];
      if ((t & 3) == 0) aks += kd;
      const f32x4* v4 = (const f32x4*)&sV[sl][te];
      acc0 += kd * v4[0];
      acc1 += kd * v4[1];
      acc2 += kd * v4[2];
      acc3 += kd * v4[3];
    }
    __syncthreads();
  }
  float* outp = pkv + ((size_t)chunk * 64 + bh) * 4096 + td * 64 + te;
  *(f32x4*)(outp + 0) = acc0;
  *(f32x4*)(outp + 4) = acc1;
  *(f32x4*)(outp + 8) = acc2;
  *(f32x4*)(outp + 12) = acc3;
  if ((t & 3) == 0) pks[((size_t)chunk * 64 + bh) * 64 + td] = aks;
}

// ---------------- reduce partials, fold division --------------------------
__global__ __launch_bounds__(256)
void kv_reduce_kernel(const float* __restrict__ pkv, const float* __restrict__ pks,
                      float* __restrict__ kvn) {
  const int bh = blockIdx.x;
  const int t = threadIdx.x;
  __shared__ float sks[64];
  if (t < 64) {
    float s = 0.f;
    for (int c = 0; c < 8; ++c) s += pks[((size_t)c * 64 + bh) * 64 + t];
    sks[t] = s + 1e-6f;
  }
  __syncthreads();
#pragma unroll
  for (int j = 0; j < 16; ++j) {
    int idx = t + j * 256;
    float s = 0.f;
    for (int c = 0; c < 8; ++c) s += pkv[((size_t)c * 64 + bh) * 4096 + idx];
    kvn[(size_t)bh * 4096 + idx] = s / sks[idx & 63];
  }
}

// ---------------- attn out: o[s,e] = sum_d q[s,d]*kvn[d,e] via MFMA -------
// grid: (64 bh, 64 s-tiles of 64 rows); block 256 (4 waves x 16 rows)
__global__ __launch_bounds__(256)
void attn_out_kernel(const u16* __restrict__ qkv, const float* __restrict__ kvn,
                     u16* __restrict__ attn) {
  const int bh = blockIdx.x;
  const int b = bh >> 4, h = bh & 15;
  const int stile = blockIdx.y;
  const int wave = threadIdx.x >> 6, lane = threadIdx.x & 63;
  const int s0 = stile * 64 + wave * 16;
  const int fr = lane & 15, fq = lane >> 4;
  __shared__ u16 sO[4][16 * 72];
  const float* kv = kvn + (size_t)bh * 4096;
  bf16x8 bfrag[2][4];
#pragma unroll
  for (int ks = 0; ks < 2; ++ks)
#pragma unroll
    for (int n = 0; n < 4; ++n) {
      u16x8 tmp;
#pragma unroll
      for (int j = 0; j < 8; ++j)
        tmp[j] = f2bf(kv[(size_t)(ks * 32 + fq * 8 + j) * 64 + n * 16 + fr]);
      bfrag[ks][n] = __builtin_bit_cast(bf16x8, tmp);
    }
  const u16* q = qkv + (size_t)b * 4096 * 3072 + h * 64;
  f32x4 acc[4] = {};
#pragma unroll
  for (int ks = 0; ks < 2; ++ks) {
    bf16x8 af = *(const bf16x8*)&q[(size_t)(s0 + fr) * 3072 + ks * 32 + fq * 8];
#pragma unroll
    for (int n = 0; n < 4; ++n)
      acc[n] = __builtin_amdgcn_mfma_f32_16x16x32_bf16(af, bfrag[ks][n], acc[n], 0, 0, 0);
  }
  // coalesced store via per-wave LDS staging
  u16* wb = &sO[wave][0];
#pragma unroll
  for (int n = 0; n < 4; ++n)
#pragma unroll
    for (int r = 0; r < 4; ++r)
      wb[(fq * 4 + r) * 72 + n * 16 + fr] = f2bf(acc[n][r]);
  u16* ap = attn + (size_t)b * 4096 * 1024 + h * 64;
  const int lrow = lane >> 3, lcol = (lane & 7) * 8;
#pragma unroll
  for (int i = 0; i < 2; ++i) {
    bf16x8 val = *(const bf16x8*)&wb[(i * 8 + lrow) * 72 + lcol];
    *(bf16x8*)&ap[(size_t)(s0 + i * 8 + lrow) * 1024 + lcol] = val;
  }
}

// -------------------------------------------------------------------------
extern "C" void kernel_launch(void* const* d_in, const int* in_sizes, int n_in,
                              void* d_out, int out_size, void* d_ws, size_t ws_size,
                              hipStream_t stream) {
  const float* x     = (const float*)d_in[0];
  const float* w_qkv = (const float*)d_in[1];
  const float* b_qkv = (const float*)d_in[2];
  const float* w_out = (const float*)d_in[3];
  const float* b_out = (const float*)d_in[4];
  float* out = (float*)d_out;

  const int M = 16384, Dm = 1024, N3 = 3072;

  char* ws = (char*)d_ws;
  u16* xb     = (u16*)(ws);                    //  33,554,432 B
  u16* wqb    = (u16*)(ws + 33554432);         //   6,291,456 B
  u16* wob    = (u16*)(ws + 39845888);         //   2,097,152 B
  u16* qkvb   = (u16*)(ws + 41943040);         // 100,663,296 B
  u16* attnb  = (u16*)(ws + 142606336);        //  33,554,432 B
  float* pkv  = (float*)(ws + 176160768);      //   8,388,608 B
  float* pks  = (float*)(ws + 184549376);      //     131,072 B
  float* kvn  = (float*)(ws + 184680448);      //   1,048,576 B

  cvt_kernel<<<(M * Dm / 4 + 255) / 256, 256, 0, stream>>>(x, xb, M * Dm / 4);
  cvt_kernel<<<(N3 * Dm / 4 + 255) / 256, 256, 0, stream>>>(w_qkv, wqb, N3 * Dm / 4);
  cvt_kernel<<<(Dm * Dm / 4 + 255) / 256, 256, 0, stream>>>(w_out, wob, Dm * Dm / 4);

  gemm256<0><<<(M / 256) * (N3 / 256), 512, 0, stream>>>(xb, wqb, b_qkv, qkvb, N3, Dm, N3 / 256);
  kv_state_kernel<<<dim3(64, 8), 256, 0, stream>>>(qkvb, pkv, pks);
  kv_reduce_kernel<<<64, 256, 0, stream>>>(pkv, pks, kvn);
  attn_out_kernel<<<dim3(64, 64), 256, 0, stream>>>(qkvb, kvn, attnb);
  gemm256<1><<<(M / 256) * (Dm / 256), 512, 0, stream>>>(attnb, wob, b_out, out, Dm, Dm, Dm / 256);
}

// Round 6
// 241.732 us; speedup vs baseline: 1.1144x; 1.0940x over previous
//
#include <hip/hip_runtime.h>
#include <stdint.h>

typedef float f32x4 __attribute__((ext_vector_type(4)));
typedef __bf16 bf16x8 __attribute__((ext_vector_type(8)));
typedef unsigned short u16;
typedef u16 u16x8 __attribute__((ext_vector_type(8)));

__device__ __forceinline__ u16 f2bf(float f) {
  uint32_t u = __builtin_bit_cast(uint32_t, f);
  return (u16)((u + 0x7fffu + ((u >> 16) & 1u)) >> 16);
}
__device__ __forceinline__ float bf2f(u16 h) {
  uint32_t u = ((uint32_t)h) << 16;
  return __builtin_bit_cast(float, u);
}
__device__ __forceinline__ float elup1(float x) {
  return x > 0.f ? x + 1.f : __expf(x);
}
__device__ __forceinline__ void gll16(const void* g, void* l) {
  __builtin_amdgcn_global_load_lds(
      (const __attribute__((address_space(1))) unsigned int*)g,
      (__attribute__((address_space(3))) unsigned int*)l, 16, 0, 0);
}

#define BAR() __builtin_amdgcn_s_barrier()
#define VMC(n) asm volatile("s_waitcnt vmcnt(" #n ")" ::: "memory")

// ---------------- fused f32 -> bf16 conversion (all 3 tensors) -----------
__global__ void cvt_all_kernel(const float* __restrict__ x, u16* __restrict__ xb,
                               const float* __restrict__ wq, u16* __restrict__ wqb,
                               const float* __restrict__ wo, u16* __restrict__ wob) {
  int i = blockIdx.x * 256 + threadIdx.x;  // float4 index, 5242880 total
  const float* in;
  u16* out;
  if (i < 4194304) {
    in = x; out = xb;
  } else if (i < 4980736) {
    in = wq; out = wqb; i -= 4194304;
  } else {
    in = wo; out = wob; i -= 4980736;
  }
  float4 f = ((const float4*)in)[i];
  ushort4 o;
  o.x = f2bf(f.x); o.y = f2bf(f.y); o.z = f2bf(f.z); o.w = f2bf(f.w);
  ((ushort4*)out)[i] = o;
}

// ============ 256x256 bf16 GEMM  C[M,N] = A[M,K]*B[N,K]^T =================
// 512 threads (8 waves, 2M x 4N). BK=64. LDS 128 KiB (2 dbuf x (A 32K + B 32K)).
// FREE-RUN schedule, 2 barriers per K-tile; STAGE issued BEFORE reads/MFMA
// in each segment (T3 recipe).
// Swizzle: stored colbyte = logical colbyte ^ ((ldsrow&7)<<4); gll dest linear,
// source pre-swizzled (rule #21).
// EPI==0: qkv epilogue (bias + elu+1 on cols<2048, bf16 store, LDS-coalesced)
// EPI==1: out epilogue (bias, f32 store — already line-coalesced)
template <int EPI>
__global__ __launch_bounds__(512, 2)
void gemm256(const u16* __restrict__ A, const u16* __restrict__ B,
             const float* __restrict__ bias, void* __restrict__ Cout,
             int N, int K, int nbj) {
  __shared__ __align__(16) u16 lds[65536];  // 128 KiB
  const int tid = threadIdx.x;
  const int wave = tid >> 6, lane = tid & 63;
  const int fr = lane & 15, fq = lane >> 4;
  const int wm = wave >> 2, wn = wave & 3;

  // XCD-aware bijective block swizzle (grid % 8 == 0 by construction)
  const int nwg = gridDim.x;
  const int cpx = nwg >> 3;
  const int swz = (blockIdx.x & 7) * cpx + (blockIdx.x >> 3);
  const int bi = swz / nbj, bj = swz % nbj;

  const u16* Ab = A + (size_t)bi * 256 * K;
  const u16* Bb = B + (size_t)bj * 256 * K;

  // staging geometry: per inst, thread covers LDS bytes i*8192 + wave*1024 + lane*16
  const int l8 = lane >> 3;                       // ldsrow & 7
  const int cswz = ((lane & 7) ^ l8) << 3;        // swizzled col offset (elements)
  const int r6 = wave * 8 + l8;                   // row within 64-row inst block

#define STAGE_A(d, h, k0)                                                      \
  { _Pragma("unroll")                                                          \
    for (int i_ = 0; i_ < 2; ++i_) {                                           \
      int gr_ = i_ * 128 + (h) * 64 + r6;                                      \
      gll16(Ab + (size_t)gr_ * K + (k0) + cswz,                                \
            &lds[((d) * 32768 + (h) * 16384 + i_ * 8192 + wave * 1024) >> 1]); \
    } }

#define STAGE_B(d, h, k0)                                                      \
  { _Pragma("unroll")                                                          \
    for (int i_ = 0; i_ < 2; ++i_) {                                           \
      int r_ = i_ * 64 + r6;                                                   \
      int gr_ = (r_ >> 5) * 64 + (h) * 32 + (r_ & 31);                         \
      gll16(Bb + (size_t)gr_ * K + (k0) + cswz,                                \
            &lds[(65536 + (d) * 32768 + (h) * 16384 + i_ * 8192 + wave * 1024) >> 1]); \
    } }

  // fragment-read addressing (bytes)
  const int xorc = (fr & 7) << 4;
  const int acol[2] = {(fq * 16) ^ xorc, (64 + fq * 16) ^ xorc};
  const int arow = (wm * 64 + fr) * 128;  // + mm*2048
  const int brow = (wn * 32 + fr) * 128;  // + nn*2048

#define LDSV(off) (*(const bf16x8*)&lds[(off) >> 1])

  f32x4 acc[8][4] = {};
  bf16x8 af[4][2];       // A frags of current m-half
  bf16x8 bfr[2][2][2];   // B frags [nh][nn][ks], both halves kept live

#define READ_A(d, mh)                                                          \
  { _Pragma("unroll")                                                          \
    for (int ks = 0; ks < 2; ++ks) {                                           \
      _Pragma("unroll")                                                        \
      for (int mm = 0; mm < 4; ++mm)                                           \
        af[mm][ks] = LDSV((d) * 32768 + (mh) * 16384 + arow + mm * 2048 + acol[ks]); \
    } }

#define READ_B(d, nh)                                                          \
  { _Pragma("unroll")                                                          \
    for (int ks = 0; ks < 2; ++ks) {                                           \
      _Pragma("unroll")                                                        \
      for (int nn = 0; nn < 2; ++nn)                                           \
        bfr[nh][nn][ks] = LDSV(65536 + (d) * 32768 + (nh) * 16384 + brow + nn * 2048 + acol[ks]); \
    } }

  // ks-outer: 8 independent MFMAs between same-acc reuses (no dep stalls)
#define MFMA_Q(mh, nh)                                                         \
  { __builtin_amdgcn_s_setprio(1);                                             \
    _Pragma("unroll")                                                          \
    for (int ks = 0; ks < 2; ++ks) {                                           \
      _Pragma("unroll")                                                        \
      for (int mm = 0; mm < 4; ++mm) {                                         \
        _Pragma("unroll")                                                      \
        for (int nn = 0; nn < 2; ++nn)                                         \
          acc[(mh) * 4 + mm][(nh) * 2 + nn] = __builtin_amdgcn_mfma_f32_16x16x32_bf16( \
              af[mm][ks], bfr[nh][nn][ks], acc[(mh) * 4 + mm][(nh) * 2 + nn], 0, 0, 0); \
      } }                                                                      \
    __builtin_amdgcn_s_setprio(0); }

  const int NT = K >> 6;
  // prologue: t0 all 4 halves, then t1's {A0,B0,B1}; one counted wait
  STAGE_A(0, 0, 0); STAGE_B(0, 0, 0); STAGE_B(0, 1, 0); STAGE_A(0, 1, 0);
  STAGE_A(1, 0, 64); STAGE_B(1, 0, 64); STAGE_B(1, 1, 64);
  VMC(6);
  BAR();

  for (int t = 0; t < NT; ++t) {
    const int d = t & 1;
    const int k1 = (t + 1) << 6, k2 = (t + 2) << 6;
    // ---- segment 1: stage first, then reads, then MFMA
    if (t + 1 < NT) STAGE_A(d ^ 1, 1, k1);
    READ_B(d, 0); READ_A(d, 0);
    MFMA_Q(0, 0);
    READ_B(d, 1);
    MFMA_Q(0, 1);
    BAR();  // MID: all waves' A0,B0,B1 reads are register-resident
    // ---- segment 2
    if (t + 2 < NT) { STAGE_A(d, 0, k2); STAGE_B(d, 0, k2); }
    READ_A(d, 1);
    MFMA_Q(1, 1);
    if (t + 2 < NT) STAGE_B(d, 1, k2);
    MFMA_Q(1, 0);
    if (t < NT - 2) { VMC(6); } else { VMC(0); }
    BAR();  // END: next tile's buffer fully landed
  }

  // ---- epilogue (after final BAR all waves are past all LDS reads)
  const int wrow = wm * 128, wcol = wn * 64;
  if (EPI == 0) {
    // block is entirely q/k (elu) or entirely v: 2048 is 256-aligned
    const bool do_elu = (bj * 256) < 2048;
    float bv[4];
#pragma unroll
    for (int n = 0; n < 4; ++n) bv[n] = bias[bj * 256 + wcol + n * 16 + fr];
    u16* wbuf = &lds[wave * 8192];  // wave-private 16 KiB
    const int lrow = lane >> 3, lcol = (lane & 7) * 8;
#pragma unroll
    for (int ch = 0; ch < 2; ++ch) {
#pragma unroll
      for (int m2 = 0; m2 < 4; ++m2)
#pragma unroll
        for (int n = 0; n < 4; ++n)
#pragma unroll
          for (int r = 0; r < 4; ++r) {
            float v = acc[ch * 4 + m2][n][r] + bv[n];
            if (do_elu) v = elup1(v);
            wbuf[(m2 * 16 + fq * 4 + r) * 72 + n * 16 + fr] = f2bf(v);
          }
      // per-wave LDS ops are in-order: cross-lane read-back is safe sans barrier
#pragma unroll
      for (int i = 0; i < 8; ++i) {
        bf16x8 val = *(const bf16x8*)&wbuf[(i * 8 + lrow) * 72 + lcol];
        const int rowg = bi * 256 + wrow + ch * 64 + i * 8 + lrow;
        *(bf16x8*)&((u16*)Cout)[(size_t)rowg * N + bj * 256 + wcol + lcol] = val;
      }
    }
  } else {
#pragma unroll
    for (int n = 0; n < 4; ++n) {
      const int colg = bj * 256 + wcol + n * 16 + fr;
      const float bv = bias[colg];
#pragma unroll
      for (int m = 0; m < 8; ++m)
#pragma unroll
        for (int r = 0; r < 4; ++r) {
          const int rowg = bi * 256 + wrow + m * 16 + fq * 4 + r;
          ((float*)Cout)[(size_t)rowg * N + colg] = acc[m][n][r] + bv;
        }
    }
  }
#undef STAGE_A
#undef STAGE_B
#undef READ_A
#undef READ_B
#undef MFMA_Q
#undef LDSV
}

// ---------------- kv state partials: kv[d][e] = sum_s k[s,d]*v[s,e] -------
// grid: (64 bh, 8 s-chunks of 512); block 256.
// 4d x 4e register blocking per thread: 16 FMA per 32 LDS-bytes read (was
// 16 FMA / 68B). K-read: 16 distinct 16B lines/wave (2-way bank = free);
// V-read: wave-broadcast (free).
__global__ __launch_bounds__(256)
void kv_state_kernel(const u16* __restrict__ qkv, float* __restrict__ pkv,
                     float* __restrict__ pks) {
  const int bh = blockIdx.x, chunk = blockIdx.y;
  const int b = bh >> 4, h = bh & 15;
  const int t = threadIdx.x;
  __shared__ float sK[16][68];
  __shared__ float sV[16][68];
  const int dg = (t & 15) * 4;   // this thread's 4 d-values
  const int eg = (t >> 4) * 4;   // this thread's 4 e-values
  f32x4 acc0 = {}, acc1 = {}, acc2 = {}, acc3 = {};
  f32x4 ak4 = {};
  const size_t rowbase = ((size_t)b * 4096 + (size_t)chunk * 512) * 3072;
  const u16* kp = qkv + rowbase + 1024 + h * 64;
  const u16* vp = qkv + rowbase + 2048 + h * 64;
  // vectorized staging: 128 threads for K, 128 for V; 16B/lane
  const int lhalf = t >> 7, lr = (t >> 3) & 15, lc = (t & 7) * 8;
  const u16* lsrc = lhalf ? vp : kp;
  float* ldst = lhalf ? &sV[lr][lc] : &sK[lr][lc];
  for (int s0 = 0; s0 < 512; s0 += 16) {
    u16x8 v8 = *(const u16x8*)&lsrc[(size_t)(s0 + lr) * 3072 + lc];
#pragma unroll
    for (int j = 0; j < 8; ++j) ldst[j] = bf2f(v8[j]);
    __syncthreads();
#pragma unroll 4
    for (int sl = 0; sl < 16; ++sl) {
      const f32x4 kv4 = *(const f32x4*)&sK[sl][dg];
      const f32x4 vv4 = *(const f32x4*)&sV[sl][eg];
      acc0 += kv4[0] * vv4;
      acc1 += kv4[1] * vv4;
      acc2 += kv4[2] * vv4;
      acc3 += kv4[3] * vv4;
      ak4 += kv4;
    }
    __syncthreads();
  }
  float* outp = pkv + ((size_t)chunk * 64 + bh) * 4096;
  *(f32x4*)&outp[(dg + 0) * 64 + eg] = acc0;
  *(f32x4*)&outp[(dg + 1) * 64 + eg] = acc1;
  *(f32x4*)&outp[(dg + 2) * 64 + eg] = acc2;
  *(f32x4*)&outp[(dg + 3) * 64 + eg] = acc3;
  if (t < 16) *(f32x4*)&pks[((size_t)chunk * 64 + bh) * 64 + dg] = ak4;
}

// ---------------- reduce partials, fold division --------------------------
__global__ __launch_bounds__(256)
void kv_reduce_kernel(const float* __restrict__ pkv, const float* __restrict__ pks,
                      float* __restrict__ kvn) {
  const int bh = blockIdx.x;
  const int t = threadIdx.x;
  __shared__ float sks[64];
  if (t < 64) {
    float s = 0.f;
    for (int c = 0; c < 8; ++c) s += pks[((size_t)c * 64 + bh) * 64 + t];
    sks[t] = s + 1e-6f;
  }
  __syncthreads();
#pragma unroll
  for (int j = 0; j < 16; ++j) {
    int idx = t + j * 256;
    float s = 0.f;
    for (int c = 0; c < 8; ++c) s += pkv[((size_t)c * 64 + bh) * 4096 + idx];
    kvn[(size_t)bh * 4096 + idx] = s / sks[idx & 63];
  }
}

// ---------------- attn out: o[s,e] = sum_d q[s,d]*kvn[d,e] via MFMA -------
// grid: (64 bh, 64 s-tiles of 64 rows); block 256 (4 waves x 16 rows)
__global__ __launch_bounds__(256)
void attn_out_kernel(const u16* __restrict__ qkv, const float* __restrict__ kvn,
                     u16* __restrict__ attn) {
  const int bh = blockIdx.x;
  const int b = bh >> 4, h = bh & 15;
  const int stile = blockIdx.y;
  const int wave = threadIdx.x >> 6, lane = threadIdx.x & 63;
  const int s0 = stile * 64 + wave * 16;
  const int fr = lane & 15, fq = lane >> 4;
  __shared__ u16 sO[4][16 * 72];
  const float* kv = kvn + (size_t)bh * 4096;
  bf16x8 bfrag[2][4];
#pragma unroll
  for (int ks = 0; ks < 2; ++ks)
#pragma unroll
    for (int n = 0; n < 4; ++n) {
      u16x8 tmp;
#pragma unroll
      for (int j = 0; j < 8; ++j)
        tmp[j] = f2bf(kv[(size_t)(ks * 32 + fq * 8 + j) * 64 + n * 16 + fr]);
      bfrag[ks][n] = __builtin_bit_cast(bf16x8, tmp);
    }
  const u16* q = qkv + (size_t)b * 4096 * 3072 + h * 64;
  f32x4 acc[4] = {};
#pragma unroll
  for (int ks = 0; ks < 2; ++ks) {
    bf16x8 af = *(const bf16x8*)&q[(size_t)(s0 + fr) * 3072 + ks * 32 + fq * 8];
#pragma unroll
    for (int n = 0; n < 4; ++n)
      acc[n] = __builtin_amdgcn_mfma_f32_16x16x32_bf16(af, bfrag[ks][n], acc[n], 0, 0, 0);
  }
  // coalesced store via per-wave LDS staging
  u16* wb = &sO[wave][0];
#pragma unroll
  for (int n = 0; n < 4; ++n)
#pragma unroll
    for (int r = 0; r < 4; ++r)
      wb[(fq * 4 + r) * 72 + n * 16 + fr] = f2bf(acc[n][r]);
  u16* ap = attn + (size_t)b * 4096 * 1024 + h * 64;
  const int lrow = lane >> 3, lcol = (lane & 7) * 8;
#pragma unroll
  for (int i = 0; i < 2; ++i) {
    bf16x8 val = *(const bf16x8*)&wb[(i * 8 + lrow) * 72 + lcol];
    *(bf16x8*)&ap[(size_t)(s0 + i * 8 + lrow) * 1024 + lcol] = val;
  }
}

// -------------------------------------------------------------------------
extern "C" void kernel_launch(void* const* d_in, const int* in_sizes, int n_in,
                              void* d_out, int out_size, void* d_ws, size_t ws_size,
                              hipStream_t stream) {
  const float* x     = (const float*)d_in[0];
  const float* w_qkv = (const float*)d_in[1];
  const float* b_qkv = (const float*)d_in[2];
  const float* w_out = (const float*)d_in[3];
  const float* b_out = (const float*)d_in[4];
  float* out = (float*)d_out;

  const int M = 16384, Dm = 1024, N3 = 3072;

  char* ws = (char*)d_ws;
  u16* xb     = (u16*)(ws);                    //  33,554,432 B
  u16* wqb    = (u16*)(ws + 33554432);         //   6,291,456 B
  u16* wob    = (u16*)(ws + 39845888);         //   2,097,152 B
  u16* qkvb   = (u16*)(ws + 41943040);         // 100,663,296 B
  u16* attnb  = (u16*)(ws + 142606336);        //  33,554,432 B
  float* pkv  = (float*)(ws + 176160768);      //   8,388,608 B
  float* pks  = (float*)(ws + 184549376);      //     131,072 B
  float* kvn  = (float*)(ws + 184680448);      //   1,048,576 B

  cvt_all_kernel<<<20480, 256, 0, stream>>>(x, xb, w_qkv, wqb, w_out, wob);

  gemm256<0><<<(M / 256) * (N3 / 256), 512, 0, stream>>>(xb, wqb, b_qkv, qkvb, N3, Dm, N3 / 256);
  kv_state_kernel<<<dim3(64, 8), 256, 0, stream>>>(qkvb, pkv, pks);
  kv_reduce_kernel<<<64, 256, 0, stream>>>(pkv, pks, kvn);
  attn_out_kernel<<<dim3(64, 64), 256, 0, stream>>>(qkvb, kvn, attnb);
  gemm256<1><<<(M / 256) * (Dm / 256), 512, 0, stream>>>(attnb, wob, b_out, out, Dm, Dm, Dm / 256);
}